// Round 3
// baseline (71.058 us; speedup 1.0000x reference)
//
#include <hip/hip_runtime.h>

// B=16384, K=32, D=128, N_ENT=100000, N_REL=64
// inputs: 0 user_emb f32[B,D], 1 entity_ids i32[B], 2 neigh_ent_ids i32[B,K],
//         3 neigh_rel_ids i32[B,K], 4 entity_table f32[N_ENT,D],
//         5 relation_table f32[N_REL,D], 6 W f32[D,D]
// out: f32[B,D]

#define BB 16384
#define KK 32
#define DD 128
#define NREL 64

typedef __attribute__((ext_vector_type(8))) short short8;
typedef __attribute__((ext_vector_type(4))) float f32x4;

static __device__ __forceinline__ short f2bf(float x) {
    unsigned u = __float_as_uint(x);
    unsigned r = (u + 0x7fff + ((u >> 16) & 1)) >> 16;  // RNE
    return (short)r;
}

// M[d][r] = sum_e rel[r,e]*W[e,d], written directly in MFMA B-fragment order:
// Mpack[(kt*4+rt)*64 + lane] = bf16x8 { M[kt*32+(lane>>4)*8+j][rt*16+(lane&15)] }
__global__ void kgnn_precompute_pack(const float* __restrict__ rel,
                                     const float* __restrict__ W,
                                     short* __restrict__ Mpack) {
    const int kt = blockIdx.x >> 2;
    const int rt = blockIdx.x & 3;
    const int lane = threadIdx.x;  // 0..63
    const int r = rt * 16 + (lane & 15);
    const int kbase = kt * 32 + ((lane >> 4) << 3);
    short8 frag;
#pragma unroll
    for (int j = 0; j < 8; ++j) {
        const int d = kbase + j;
        float acc = 0.f;
#pragma unroll 8
        for (int e = 0; e < DD; ++e) acc = fmaf(rel[r * DD + e], W[e * DD + d], acc);
        frag[j] = f2bf(acc);
    }
    ((short8*)Mpack)[blockIdx.x * 64 + lane] = frag;
}

// all_scores[b][r] = u[b].M[r] via mfma_f32_16x16x32_bf16. Wave = 16 rows x 64 rels.
__global__ __launch_bounds__(256) void kgnn_scores(
    const float* __restrict__ user_emb,
    const short* __restrict__ Mpack,
    float* __restrict__ all_scores) {
    const int tid = threadIdx.x;
    const int wave = tid >> 6;
    const int lane = tid & 63;
    const int rowbase = blockIdx.x * 64 + wave * 16;

    const short8* mp = (const short8*)Mpack;
    f32x4 acc[4];
#pragma unroll
    for (int rt = 0; rt < 4; ++rt) acc[rt] = (f32x4){0.f, 0.f, 0.f, 0.f};

    const int arow = rowbase + (lane & 15);
    const int koff = (lane >> 4) << 3;

#pragma unroll
    for (int kt = 0; kt < 4; ++kt) {
        // A-frag: 8 consecutive k of this lane's row
        const float4* up = (const float4*)(user_emb + arow * DD + kt * 32 + koff);
        const float4 a0 = up[0], a1 = up[1];
        short8 af;
        af[0] = f2bf(a0.x); af[1] = f2bf(a0.y); af[2] = f2bf(a0.z); af[3] = f2bf(a0.w);
        af[4] = f2bf(a1.x); af[5] = f2bf(a1.y); af[6] = f2bf(a1.z); af[7] = f2bf(a1.w);
#pragma unroll
        for (int rt = 0; rt < 4; ++rt) {
            const short8 bf = mp[(kt * 4 + rt) * 64 + lane];
            acc[rt] = __builtin_amdgcn_mfma_f32_16x16x32_bf16(af, bf, acc[rt], 0, 0, 0);
        }
    }

    // C/D: col = lane&15, row = (lane>>4)*4 + i  [m89]
    const int srow = rowbase + ((lane >> 4) << 2);
    const int scol = lane & 15;
#pragma unroll
    for (int rt = 0; rt < 4; ++rt) {
#pragma unroll
        for (int i = 0; i < 4; ++i) {
            all_scores[(srow + i) * NREL + rt * 16 + scol] = acc[rt][i];
        }
    }
}

// Hot kernel: gather + softmax + weighted sum. 2 rows per wave, full unroll,
// readlane(SGPR)-based uniform addressing for max loads in flight.
__global__ __launch_bounds__(256, 4) void kgnn_agg(
    const int* __restrict__ entity_ids,
    const int* __restrict__ neigh_ent,
    const int* __restrict__ neigh_rel,
    const float* __restrict__ entity_table,
    const float* __restrict__ all_scores,
    float* __restrict__ out) {
    const int tid = threadIdx.x;
    const int wave = tid >> 6;
    const int lane = tid & 63;
    const int row0 = blockIdx.x * 8 + wave * 2;
    const int row1 = row0 + 1;
    const int k = lane & 31;

    const int rid0 = neigh_rel[row0 * KK + k];
    const int rid1 = neigh_rel[row1 * KK + k];
    const int eid0 = neigh_ent[row0 * KK + k];
    const int eid1 = neigh_ent[row1 * KK + k];

    // self rows issued early
    const int se0 = entity_ids[row0];
    const int se1 = entity_ids[row1];
    const float2 s20 = ((const float2*)(entity_table + (long long)se0 * DD))[lane];
    const float2 s21 = ((const float2*)(entity_table + (long long)se1 * DD))[lane];

    float p0 = all_scores[row0 * NREL + rid0];
    float p1 = all_scores[row1 * NREL + rid1];

    // softmax over k (halves duplicate; xor masks <32 stay within half)
    float m0 = p0, m1 = p1;
#pragma unroll
    for (int m = 16; m >= 1; m >>= 1) {
        m0 = fmaxf(m0, __shfl_xor(m0, m));
        m1 = fmaxf(m1, __shfl_xor(m1, m));
    }
    float w0 = __expf(p0 - m0);
    float w1 = __expf(p1 - m1);
    float t0 = w0, t1 = w1;
#pragma unroll
    for (int m = 16; m >= 1; m >>= 1) {
        t0 += __shfl_xor(t0, m);
        t1 += __shfl_xor(t1, m);
    }
    w0 /= t0;
    w1 /= t1;

    float2 acc0 = {0.f, 0.f}, acc1 = {0.f, 0.f};
#pragma unroll
    for (int kk2 = 0; kk2 < KK; ++kk2) {
        const int e0 = __builtin_amdgcn_readlane(eid0, kk2);
        const int e1 = __builtin_amdgcn_readlane(eid1, kk2);
        const float wk0 = __uint_as_float(__builtin_amdgcn_readlane(__float_as_uint(w0), kk2));
        const float wk1 = __uint_as_float(__builtin_amdgcn_readlane(__float_as_uint(w1), kk2));
        const float2 v0 = ((const float2*)(entity_table + (long long)e0 * DD))[lane];
        const float2 v1 = ((const float2*)(entity_table + (long long)e1 * DD))[lane];
        acc0.x = fmaf(wk0, v0.x, acc0.x);
        acc0.y = fmaf(wk0, v0.y, acc0.y);
        acc1.x = fmaf(wk1, v1.x, acc1.x);
        acc1.y = fmaf(wk1, v1.y, acc1.y);
    }

    float2 o0, o1;
    o0.x = fmaxf(0.f, s20.x + acc0.x);
    o0.y = fmaxf(0.f, s20.y + acc0.y);
    o1.x = fmaxf(0.f, s21.x + acc1.x);
    o1.y = fmaxf(0.f, s21.y + acc1.y);
    ((float2*)(out + (long long)row0 * DD))[lane] = o0;
    ((float2*)(out + (long long)row1 * DD))[lane] = o1;
}

extern "C" void kernel_launch(void* const* d_in, const int* in_sizes, int n_in,
                              void* d_out, int out_size, void* d_ws, size_t ws_size,
                              hipStream_t stream) {
    const float* user_emb = (const float*)d_in[0];
    const int* entity_ids = (const int*)d_in[1];
    const int* neigh_ent = (const int*)d_in[2];
    const int* neigh_rel = (const int*)d_in[3];
    const float* entity_table = (const float*)d_in[4];
    const float* relation_table = (const float*)d_in[5];
    const float* W = (const float*)d_in[6];
    float* out = (float*)d_out;

    short* Mpack = (short*)d_ws;                                // 16 KB
    float* all_scores = (float*)((char*)d_ws + 16384);          // 4.2 MB

    kgnn_precompute_pack<<<16, 64, 0, stream>>>(relation_table, W, Mpack);
    kgnn_scores<<<BB / 64, 256, 0, stream>>>(user_emb, Mpack, all_scores);
    kgnn_agg<<<BB / 8, 256, 0, stream>>>(entity_ids, neigh_ent, neigh_rel,
                                         entity_table, all_scores, out);
}

// Round 4
// 47.802 us; speedup vs baseline: 1.4865x; 1.4865x over previous
//
#include <hip/hip_runtime.h>
#include <hip/hip_fp16.h>

// B=16384, K=32, D=128, N_ENT=100000, N_REL=64
// inputs: 0 user_emb f32[B,D], 1 entity_ids i32[B], 2 neigh_ent_ids i32[B,K],
//         3 neigh_rel_ids i32[B,K], 4 entity_table f32[N_ENT,D],
//         5 relation_table f32[N_REL,D], 6 W f32[D,D]
// out: f32[B,D]

#define BB 16384
#define KK 32
#define DD 128
#define NENT 100000
#define NREL 64

typedef __attribute__((ext_vector_type(8))) short short8;
typedef __attribute__((ext_vector_type(4))) float f32x4;

static __device__ __forceinline__ short f2bf(float x) {
    unsigned u = __float_as_uint(x);
    unsigned r = (u + 0x7fff + ((u >> 16) & 1)) >> 16;  // RNE
    return (short)r;
}

// M[r][d] = sum_e rel[r,e]*W[e,d], stored straight into the MFMA B-frag pack:
// for (r,d): kt=d>>5, rt=r>>4, lane=((d>>3)&3)*16+(r&15), j=d&7
// Mpack short index = ((kt*4+rt)*64+lane)*8 + j
__global__ void kgnn_precompute_pack(const float* __restrict__ rel,
                                     const float* __restrict__ W,
                                     short* __restrict__ Mpack) {
    __shared__ float rrow[DD];
    const int r = blockIdx.x;   // 0..63
    const int d = threadIdx.x;  // 0..127
    rrow[d] = rel[r * DD + d];
    __syncthreads();
    float acc = 0.f;
#pragma unroll 8
    for (int e = 0; e < DD; ++e) acc = fmaf(rrow[e], W[e * DD + d], acc);
    const int kt = d >> 5, rt = r >> 4;
    const int lane = (((d >> 3) & 3) << 4) | (r & 15);
    const int j = d & 7;
    Mpack[(((kt * 4 + rt) * 64 + lane) << 3) + j] = f2bf(acc);
}

// entity_table f32 -> fp16 (halves all gather bytes in the hot kernel)
__global__ __launch_bounds__(256) void kgnn_convert(const float* __restrict__ src,
                                                    __half* __restrict__ dst) {
    const int n4 = NENT * DD / 4;  // 3.2M float4 chunks
    const int stride = gridDim.x * 256;
    for (int i = blockIdx.x * 256 + threadIdx.x; i < n4; i += stride) {
        const float4 v = ((const float4*)src)[i];
        __half2 a = __floats2half2_rn(v.x, v.y);
        __half2 b = __floats2half2_rn(v.z, v.w);
        uint2 o;
        o.x = *(const unsigned int*)&a;
        o.y = *(const unsigned int*)&b;
        ((uint2*)dst)[i] = o;
    }
}

// all_scores[b][r] = u[b].M[r] via mfma_f32_16x16x32_bf16. Wave = 16 rows x 64 rels.
__global__ __launch_bounds__(256) void kgnn_scores(
    const float* __restrict__ user_emb,
    const short* __restrict__ Mpack,
    float* __restrict__ all_scores) {
    const int tid = threadIdx.x;
    const int wave = tid >> 6;
    const int lane = tid & 63;
    const int rowbase = blockIdx.x * 64 + wave * 16;

    const short8* mp = (const short8*)Mpack;
    f32x4 acc[4];
#pragma unroll
    for (int rt = 0; rt < 4; ++rt) acc[rt] = (f32x4){0.f, 0.f, 0.f, 0.f};

    const int arow = rowbase + (lane & 15);
    const int koff = (lane >> 4) << 3;

#pragma unroll
    for (int kt = 0; kt < 4; ++kt) {
        const float4* up = (const float4*)(user_emb + arow * DD + kt * 32 + koff);
        const float4 a0 = up[0], a1 = up[1];
        short8 af;
        af[0] = f2bf(a0.x); af[1] = f2bf(a0.y); af[2] = f2bf(a0.z); af[3] = f2bf(a0.w);
        af[4] = f2bf(a1.x); af[5] = f2bf(a1.y); af[6] = f2bf(a1.z); af[7] = f2bf(a1.w);
#pragma unroll
        for (int rt = 0; rt < 4; ++rt) {
            const short8 bf = mp[(kt * 4 + rt) * 64 + lane];
            acc[rt] = __builtin_amdgcn_mfma_f32_16x16x32_bf16(af, bf, acc[rt], 0, 0, 0);
        }
    }

    const int srow = rowbase + ((lane >> 4) << 2);
    const int scol = lane & 15;
#pragma unroll
    for (int rt = 0; rt < 4; ++rt) {
#pragma unroll
        for (int i = 0; i < 4; ++i) {
            all_scores[(srow + i) * NREL + rt * 16 + scol] = acc[rt][i];
        }
    }
}

// Hot kernel: gather(fp16) + softmax + weighted sum. 1 row/wave, two-phase
// fully-unrolled gather (32 loads in flight), readlane broadcasts.
__global__ __launch_bounds__(256, 4) void kgnn_agg(
    const int* __restrict__ entity_ids,
    const int* __restrict__ neigh_ent,
    const int* __restrict__ neigh_rel,
    const __half* __restrict__ et16,
    const float* __restrict__ all_scores,
    float* __restrict__ out) {
    const int tid = threadIdx.x;
    const int wave = tid >> 6;
    const int lane = tid & 63;
    const int row = blockIdx.x * 4 + wave;
    const int k = lane & 31;

    const int rid = neigh_rel[row * KK + k];
    const int eid = neigh_ent[row * KK + k];
    const int se = entity_ids[row];

    // self row (half2 per lane), issued early
    const unsigned int sv = ((const unsigned int*)(et16 + (long long)se * DD))[lane];

    float p = all_scores[row * NREL + rid];

    // softmax over k (halves duplicate; xor masks <32 stay within half)
    float mx = p;
#pragma unroll
    for (int m = 16; m >= 1; m >>= 1) mx = fmaxf(mx, __shfl_xor(mx, m));
    float w = __expf(p - mx);
    float s = w;
#pragma unroll
    for (int m = 16; m >= 1; m >>= 1) s += __shfl_xor(s, m);
    w /= s;

    // phase 1: issue all 32 gathers
    unsigned int ev[KK];
#pragma unroll
    for (int kk2 = 0; kk2 < KK; ++kk2) {
        const int e = __builtin_amdgcn_readlane(eid, kk2);
        ev[kk2] = ((const unsigned int*)(et16 + (long long)e * DD))[lane];
    }

    // phase 2: weighted accumulate
    float2 acc = {0.f, 0.f};
#pragma unroll
    for (int kk2 = 0; kk2 < KK; ++kk2) {
        const float wk = __uint_as_float(__builtin_amdgcn_readlane(__float_as_uint(w), kk2));
        const __half2 h = *(const __half2*)&ev[kk2];
        const float2 v = __half22float2(h);
        acc.x = fmaf(wk, v.x, acc.x);
        acc.y = fmaf(wk, v.y, acc.y);
    }

    const float2 sf = __half22float2(*(const __half2*)&sv);
    float2 o;
    o.x = fmaxf(0.f, sf.x + acc.x);
    o.y = fmaxf(0.f, sf.y + acc.y);
    ((float2*)(out + (long long)row * DD))[lane] = o;
}

extern "C" void kernel_launch(void* const* d_in, const int* in_sizes, int n_in,
                              void* d_out, int out_size, void* d_ws, size_t ws_size,
                              hipStream_t stream) {
    const float* user_emb = (const float*)d_in[0];
    const int* entity_ids = (const int*)d_in[1];
    const int* neigh_ent = (const int*)d_in[2];
    const int* neigh_rel = (const int*)d_in[3];
    const float* entity_table = (const float*)d_in[4];
    const float* relation_table = (const float*)d_in[5];
    const float* W = (const float*)d_in[6];
    float* out = (float*)d_out;

    short* Mpack = (short*)d_ws;                               // 16 KB
    float* all_scores = (float*)((char*)d_ws + 16384);         // 4.2 MB
    __half* et16 = (__half*)((char*)d_ws + 16384 + 4194304);   // 25.6 MB

    kgnn_precompute_pack<<<NREL, DD, 0, stream>>>(relation_table, W, Mpack);
    kgnn_convert<<<2048, 256, 0, stream>>>(entity_table, et16);
    kgnn_scores<<<BB / 64, 256, 0, stream>>>(user_emb, Mpack, all_scores);
    kgnn_agg<<<BB / 4, 256, 0, stream>>>(entity_ids, neigh_ent, neigh_rel,
                                         et16, all_scores, out);
}